// Round 13
// baseline (978.034 us; speedup 1.0000x reference)
//
#include <hip/hip_runtime.h>
#include <hip/hip_bf16.h>

// Problem constants
#define NB 16384        // batch rows
#define TEXT_D 768
#define TECH_D 256
#define IND 1024        // IN_D
#define OUTD 1024       // OUT_D
#define NE 8            // experts
#define KH2 4096        // half-hidden K = 4 experts * 1024

typedef unsigned short u16;
typedef __bf16 bf16x8 __attribute__((ext_vector_type(8)));
typedef float f32x4 __attribute__((ext_vector_type(4)));

__device__ __forceinline__ u16 f2bf(float f) {
  union { float f; unsigned int u; } x; x.f = f;
  unsigned int u = x.u;
  return (u16)((u + 0x7FFFu + ((u >> 16) & 1u)) >> 16);
}

__device__ __forceinline__ void gload_lds16(const void* g, void* l) {
  __builtin_amdgcn_global_load_lds(
      (const __attribute__((address_space(1))) unsigned int*)g,
      (__attribute__((address_space(3))) unsigned int*)l, 16, 0, 0);
}

// ---------------------------------------------------------------------------
// Fused: concat->bf16 xb  AND  gates = softmax(x@Wg + bg).
// ---------------------------------------------------------------------------
__global__ __launch_bounds__(256) void convert_gates(
    const float* __restrict__ text, const float* __restrict__ tech,
    const float* __restrict__ Wg, const float* __restrict__ bg,
    u16* __restrict__ xb, float* __restrict__ gates) {
  int t = threadIdx.x;
  int wave = t >> 6, lane = t & 63;
  int row = blockIdx.x * 4 + wave;

  float acc[NE];
#pragma unroll
  for (int e = 0; e < NE; ++e) acc[e] = 0.f;

#pragma unroll
  for (int j = 0; j < 4; ++j) {
    int col = j * 256 + lane * 4;
    float4 v = (j < 3) ? *(const float4*)&text[(size_t)row * TEXT_D + col]
                       : *(const float4*)&tech[(size_t)row * TECH_D + lane * 4];
    ushort4 o = make_ushort4(f2bf(v.x), f2bf(v.y), f2bf(v.z), f2bf(v.w));
    *(ushort4*)&xb[(size_t)row * IND + col] = o;
    const float* wp = &Wg[(size_t)col * NE];
    float xv[4] = {v.x, v.y, v.z, v.w};
#pragma unroll
    for (int i = 0; i < 4; ++i) {
      float4 w0 = *(const float4*)&wp[i * NE];
      float4 w1 = *(const float4*)&wp[i * NE + 4];
      acc[0] = fmaf(xv[i], w0.x, acc[0]);
      acc[1] = fmaf(xv[i], w0.y, acc[1]);
      acc[2] = fmaf(xv[i], w0.z, acc[2]);
      acc[3] = fmaf(xv[i], w0.w, acc[3]);
      acc[4] = fmaf(xv[i], w1.x, acc[4]);
      acc[5] = fmaf(xv[i], w1.y, acc[5]);
      acc[6] = fmaf(xv[i], w1.z, acc[6]);
      acc[7] = fmaf(xv[i], w1.w, acc[7]);
    }
  }
#pragma unroll
  for (int off = 32; off; off >>= 1)
#pragma unroll
    for (int e = 0; e < NE; ++e) acc[e] += __shfl_xor(acc[e], off);

#pragma unroll
  for (int e = 0; e < NE; ++e) acc[e] += bg[e];
  float mx = acc[0];
#pragma unroll
  for (int e = 1; e < NE; ++e) mx = fmaxf(mx, acc[e]);
  float s = 0.f;
#pragma unroll
  for (int e = 0; e < NE; ++e) { acc[e] = expf(acc[e] - mx); s += acc[e]; }
  float inv = 1.f / s;
  if (lane < NE) gates[(size_t)row * NE + lane] = acc[lane] * inv;
}

// ---------------------------------------------------------------------------
// Transpose fp32 W -> bf16, both weights in one dispatch.
//   blocks [0,2048):   W1[e][k][n] -> W1t[e][n*1024 + k]      (k linear)
//   blocks [2048,4096): W2[e][k][n] -> W2t[e>>2][n*4096 + (e&3)*1024 + k']
//     with k' within each 64-block: k = 16b + s -> k' = 4s + b  (matches
//     gemm1's coalesced Hg store; dot product invariant)
// ---------------------------------------------------------------------------
__global__ __launch_bounds__(256) void transpose_w12(
    const float* __restrict__ W1, const float* __restrict__ W2,
    u16* __restrict__ W1t, u16* __restrict__ W2t) {
  __shared__ u16 tile[64][65];
  int bid = blockIdx.x;
  int half = bid >> 11;
  int b2 = bid & 2047;
  int e = b2 >> 8;
  int tb = b2 & 255;
  int r0 = (tb >> 4) * 64;     // input row block (k)
  int c0 = (tb & 15) * 64;     // input col block (n)
  const float* We; u16* Wte; int ostride;
  if (half == 0) {
    We = W1 + (size_t)e * IND * OUTD;
    Wte = W1t + ((size_t)e << 20);
    ostride = 1024;
  } else {
    We = W2 + (size_t)e * IND * OUTD;
    Wte = W2t + ((size_t)(e >> 2) << 22) + (size_t)(e & 3) * 1024;
    ostride = KH2;
  }
  int t = threadIdx.x;
  int tr = t >> 4;
  int s  = t & 15;
  int tc = s * 4;
#pragma unroll
  for (int j = 0; j < 4; ++j) {
    int row = j * 16 + tr;
    float4 v = *(const float4*)&We[(size_t)(r0 + row) * OUTD + c0 + tc];
    tile[row][tc + 0] = f2bf(v.x);
    tile[row][tc + 1] = f2bf(v.y);
    tile[row][tc + 2] = f2bf(v.z);
    tile[row][tc + 3] = f2bf(v.w);
  }
  __syncthreads();
#pragma unroll
  for (int j = 0; j < 4; ++j) {
    int row = j * 16 + tr;     // output row (= input col n)
    ushort4 o;
    if (half == 0) {
      o = make_ushort4(tile[tc + 0][row], tile[tc + 1][row],
                       tile[tc + 2][row], tile[tc + 3][row]);
    } else {
      // k' = 4s + b  <-  k = 16b + s
      o = make_ushort4(tile[s][row], tile[s + 16][row],
                       tile[s + 32][row], tile[s + 48][row]);
    }
    *(ushort4*)&Wte[(size_t)(c0 + row) * ostride + r0 + tc] = o;
  }
}

// ---------------------------------------------------------------------------
// 128x256 GEMM core, BK=32, 4 waves (2x2), 72 KiB LDS (3 x 24KB buffers),
// 2 blocks/CU (__launch_bounds__(256,2)): inter-block overlap supplies the
// DS<->MFMA concurrency that the 1-block/CU 8-wave design never achieved
// (r4-r12: tile time == DS + MFMA serial).
// LDS layout (chunk-major, NO swizzle needed):
//   A buf (8KB):  addr = hic*2048 + row*16   (row in [0,128), hic = k-chunk)
//   B buf (16KB): addr = hic*4096 + nrow*16  (nrow in [0,256))
// Staging: per thread 6 x gload_lds16; dest = base + d*16 (linear in lane,
// wave-uniform base); per-lane SOURCE gathers the matching [row][k-chunk].
// Frag reads: lane(lr,hi) reads chunk hi, row ..+lr -> 256B contiguous per
// hi-group -> conflict-free by construction.
// Tile T: { stage S(T+2); VM12 -> S(T) complete (2-tile flight ~2000cyc);
//           BAR; 12 ds_read_b128; 32 independent MFMA; BAR }
// Tail: T=KT-2: VM6 -> S(KT-2); T=KT-1: VM0.
// ---------------------------------------------------------------------------
#define BAR() asm volatile("s_barrier" ::: "memory")
#define VM0()  asm volatile("s_waitcnt vmcnt(0)" ::: "memory")
#define VM6()  asm volatile("s_waitcnt vmcnt(6)" ::: "memory")
#define VM12() asm volatile("s_waitcnt vmcnt(12)" ::: "memory")

template <int K>
__device__ __forceinline__ void stage_tile(
    const u16* __restrict__ pA, const u16* __restrict__ pB,
    char* lds, int T, int t) {
  int kb = T * 32;
  char* base = lds + (T % 3) * 24576;
  // A: 128 rows x 32k; 512 chunks of 16B; thread t does d = t, t+256
#pragma unroll
  for (int j = 0; j < 2; ++j) {
    int d = t + 256 * j;
    gload_lds16(pA + (size_t)(d & 127) * K + kb + (d >> 7) * 8, base + d * 16);
  }
  // B: 256 rows x 32k; 1024 chunks; thread t does rows t, chunks j=0..3
#pragma unroll
  for (int j = 0; j < 4; ++j)
    gload_lds16(pB + (size_t)t * K + kb + j * 8,
                base + 8192 + (t + 256 * j) * 16);
}

// ---------------------------------------------------------------------------
template <int K>
__device__ __forceinline__ void core128x256(const u16* __restrict__ pA,
                                            const u16* __restrict__ pB,
                                            char* lds, int t,
                                            f32x4 (&acc)[4][8]) {
  constexpr int KT = K / 32;
  static_assert(KT >= 2, "KT >= 2");
  const int l = t & 63;
  const int w = t >> 6;
  const int wr = w >> 1, wc = w & 1;
  const int lr = l & 15, hi = l >> 4;

  // prologue: stage tiles 0 and 1
  stage_tile<K>(pA, pB, lds, 0, t);
  stage_tile<K>(pA, pB, lds, 1, t);

  for (int T = 0; T < KT; ++T) {
    if (T + 2 < KT) {
      stage_tile<K>(pA, pB, lds, T + 2, t);
      VM12();                 // S(T) complete (12 newer loads outstanding)
    } else if (T + 1 < KT) {
      VM6();                  // S(KT-2) complete
    } else {
      VM0();                  // S(KT-1) complete
    }
    BAR();
    const char* rb = lds + (T % 3) * 24576;
    bf16x8 a[4], b[8];
#pragma unroll
    for (int i = 0; i < 4; ++i)
      a[i] = *(const bf16x8*)(rb + hi * 2048 + (wr * 64 + i * 16 + lr) * 16);
#pragma unroll
    for (int n = 0; n < 8; ++n)
      b[n] = *(const bf16x8*)(rb + 8192 + hi * 4096 +
                              (wc * 128 + n * 16 + lr) * 16);
    __builtin_amdgcn_s_setprio(1);
#pragma unroll
    for (int i = 0; i < 4; ++i)
#pragma unroll
      for (int n = 0; n < 8; ++n)
        acc[i][n] = __builtin_amdgcn_mfma_f32_16x16x32_bf16(a[i], b[n],
                                                            acc[i][n], 0, 0, 0);
    __builtin_amdgcn_s_setprio(0);
    BAR();
  }
}

// ---------------------------------------------------------------------------
// GEMM1 (one expert-half, 4 experts, full batch):
//   Hg[m][ee*1024 + perm64(n)] = gates[m][eg0+ee]*relu(x@W1_[eg0+ee] + b1)
// perm64 (r9): within each 64-col block, n = 16b+s stored at 4s+b ->
// thread's 4 nn-values per 64-block are consecutive -> ushort4 stores.
// grid = 128mb * 16nt = 2048; tile 128x256.
// ---------------------------------------------------------------------------
__global__ __launch_bounds__(256, 2) void gemm1(
    const u16* __restrict__ xb, const u16* __restrict__ W1t,
    const float* __restrict__ b1, const float* __restrict__ gates,
    u16* __restrict__ Hg, int eg0) {
  __shared__ char lds[73728];
  int t = threadIdx.x;
  int nwg = gridDim.x, cpx = nwg >> 3, bid = blockIdx.x;
  int swz = (bid & 7) * cpx + (bid >> 3);  // bijective XCD swizzle (nwg%8==0)
  int nt = swz & 15, mb = swz >> 4;

  int colbase = nt * 256;                  // within half's 4096-col space
  int ee = colbase >> 10;
  int e = eg0 + ee;

  f32x4 acc[4][8] = {};
  core128x256<1024>(xb + (size_t)mb * 128 * 1024,
                    W1t + ((size_t)e << 20) + (size_t)(colbase & 1023) * 1024,
                    lds, t, acc);

  int l = t & 63, w = t >> 6, wr = w >> 1, wc = w & 1, lr = l & 15, hi = l >> 4;
  int m0 = mb * 128 + wr * 64 + hi * 4;
  int ne0 = (colbase & 1023) + wc * 128;   // 128-aligned within expert
  const float* b1e = b1 + e * OUTD;
  float bv[8];
#pragma unroll
  for (int nn = 0; nn < 8; ++nn) bv[nn] = b1e[ne0 + nn * 16 + lr];
#pragma unroll
  for (int i = 0; i < 4; ++i) {
#pragma unroll
    for (int r = 0; r < 4; ++r) {
      int row = m0 + i * 16 + r;
      float g = gates[(size_t)row * NE + e];
      ushort4 o1, o2;
      o1.x = f2bf(g * fmaxf(acc[i][0][r] + bv[0], 0.f));
      o1.y = f2bf(g * fmaxf(acc[i][1][r] + bv[1], 0.f));
      o1.z = f2bf(g * fmaxf(acc[i][2][r] + bv[2], 0.f));
      o1.w = f2bf(g * fmaxf(acc[i][3][r] + bv[3], 0.f));
      o2.x = f2bf(g * fmaxf(acc[i][4][r] + bv[4], 0.f));
      o2.y = f2bf(g * fmaxf(acc[i][5][r] + bv[5], 0.f));
      o2.z = f2bf(g * fmaxf(acc[i][6][r] + bv[6], 0.f));
      o2.w = f2bf(g * fmaxf(acc[i][7][r] + bv[7], 0.f));
      size_t base = (size_t)row * KH2 + ee * 1024 + ne0;
      *(ushort4*)&Hg[base + 4 * lr]      = o1;   // 64-block 0: k' = 4lr+nn
      *(ushort4*)&Hg[base + 64 + 4 * lr] = o2;   // 64-block 1
    }
  }
}

// ---------------------------------------------------------------------------
// GEMM2 (one expert-half, K=4096, k-permuted A and B consistently):
//   FIRST: out = Hg@W2th + sum_{ee<4} g*b2 ;  else out += same
// grid = 128mb * 4nt = 512; tile 128x256.
// ---------------------------------------------------------------------------
template <bool FIRST>
__global__ __launch_bounds__(256, 2) void gemm2(
    const u16* __restrict__ Hg, const u16* __restrict__ W2th,
    const float* __restrict__ b2h, const float* __restrict__ gates,
    float* __restrict__ out, int eg0) {
  __shared__ char lds[73728];
  int t = threadIdx.x;
  int nwg = gridDim.x, cpx = nwg >> 3, bid = blockIdx.x;
  int swz = (bid & 7) * cpx + (bid >> 3);
  int nt = swz & 3, mb = swz >> 2;

  f32x4 acc[4][8] = {};
  core128x256<KH2>(Hg + (size_t)mb * 128 * KH2,
                   W2th + (size_t)nt * 256 * KH2, lds, t, acc);

  int l = t & 63, w = t >> 6, wr = w >> 1, wc = w & 1, lr = l & 15, hi = l >> 4;
  int m0 = mb * 128 + wr * 64 + hi * 4;
  int n0 = nt * 256 + wc * 128 + lr;

  float bcol[8][4];
#pragma unroll
  for (int nn = 0; nn < 8; ++nn)
#pragma unroll
    for (int j = 0; j < 4; ++j)
      bcol[nn][j] = b2h[j * OUTD + n0 + nn * 16];

#pragma unroll
  for (int i = 0; i < 4; ++i) {
#pragma unroll
    for (int r = 0; r < 4; ++r) {
      int row = m0 + i * 16 + r;
      float4 ga = *(const float4*)&gates[(size_t)row * NE + eg0];
#pragma unroll
      for (int nn = 0; nn < 8; ++nn) {
        float bias = ga.x * bcol[nn][0] + ga.y * bcol[nn][1] +
                     ga.z * bcol[nn][2] + ga.w * bcol[nn][3];
        size_t oi = (size_t)row * OUTD + n0 + nn * 16;
        float v = acc[i][nn][r] + bias;
        if (FIRST) out[oi] = v;
        else       out[oi] += v;
      }
    }
  }
}

// ---------------------------------------------------------------------------
extern "C" void kernel_launch(void* const* d_in, const int* in_sizes, int n_in,
                              void* d_out, int out_size, void* d_ws, size_t ws_size,
                              hipStream_t stream) {
  (void)in_sizes; (void)n_in; (void)out_size; (void)ws_size;
  const float* text = (const float*)d_in[0];
  const float* tech = (const float*)d_in[1];
  const float* W1   = (const float*)d_in[2];
  const float* b1   = (const float*)d_in[3];
  const float* W2   = (const float*)d_in[4];
  const float* b2   = (const float*)d_in[5];
  const float* Wg   = (const float*)d_in[6];
  const float* bg   = (const float*)d_in[7];
  float* out = (float*)d_out;

  // workspace: 33.5 + 16.8 + 16.8 + 0.5 + 134.2 = 201.85 MB (proven fits)
  char* p = (char*)d_ws;
  u16* xb  = (u16*)p;  p += (size_t)NB * IND * 2;
  u16* W1t = (u16*)p;  p += (size_t)NE * IND * OUTD * 2;
  u16* W2t = (u16*)p;  p += (size_t)NE * OUTD * OUTD * 2;  // 2 halves x [1024][4096]
  float* gates = (float*)p; p += (size_t)NB * NE * 4;
  u16* Hg  = (u16*)p;                                      // [NB][KH2] bf16

  convert_gates<<<dim3(NB / 4), dim3(256), 0, stream>>>(text, tech, Wg, bg, xb, gates);
  transpose_w12<<<dim3(4096), dim3(256), 0, stream>>>(W1, W2, W1t, W2t);

  for (int h = 0; h < 2; ++h) {
    int eg0 = h * 4;
    gemm1<<<dim3(2048), dim3(256), 0, stream>>>(xb, W1t, b1, gates, Hg, eg0);
    const u16* W2th = W2t + ((size_t)h << 22);
    const float* b2h = b2 + (size_t)eg0 * OUTD;
    if (h == 0)
      gemm2<true><<<dim3(512), dim3(256), 0, stream>>>(Hg, W2th, b2h, gates, out, eg0);
    else
      gemm2<false><<<dim3(512), dim3(256), 0, stream>>>(Hg, W2th, b2h, gates, out, eg0);
  }
}

// Round 14
// 571.869 us; speedup vs baseline: 1.7102x; 1.7102x over previous
//
#include <hip/hip_runtime.h>
#include <hip/hip_bf16.h>

// Problem constants
#define NB 16384        // batch rows
#define TEXT_D 768
#define TECH_D 256
#define IND 1024        // IN_D
#define OUTD 1024       // OUT_D
#define NE 8            // experts
#define KH2 4096        // half-hidden K = 4 experts * 1024

typedef unsigned short u16;
typedef __bf16 bf16x8 __attribute__((ext_vector_type(8)));
typedef float f32x4 __attribute__((ext_vector_type(4)));

__device__ __forceinline__ u16 f2bf(float f) {
  union { float f; unsigned int u; } x; x.f = f;
  unsigned int u = x.u;
  return (u16)((u + 0x7FFFu + ((u >> 16) & 1u)) >> 16);
}

__device__ __forceinline__ void gload_lds16(const void* g, void* l) {
  __builtin_amdgcn_global_load_lds(
      (const __attribute__((address_space(1))) unsigned int*)g,
      (__attribute__((address_space(3))) unsigned int*)l, 16, 0, 0);
}

// ---------------------------------------------------------------------------
// Fused: concat->bf16 xb  AND  gates = softmax(x@Wg + bg).
// ---------------------------------------------------------------------------
__global__ __launch_bounds__(256) void convert_gates(
    const float* __restrict__ text, const float* __restrict__ tech,
    const float* __restrict__ Wg, const float* __restrict__ bg,
    u16* __restrict__ xb, float* __restrict__ gates) {
  int t = threadIdx.x;
  int wave = t >> 6, lane = t & 63;
  int row = blockIdx.x * 4 + wave;

  float acc[NE];
#pragma unroll
  for (int e = 0; e < NE; ++e) acc[e] = 0.f;

#pragma unroll
  for (int j = 0; j < 4; ++j) {
    int col = j * 256 + lane * 4;
    float4 v = (j < 3) ? *(const float4*)&text[(size_t)row * TEXT_D + col]
                       : *(const float4*)&tech[(size_t)row * TECH_D + lane * 4];
    ushort4 o = make_ushort4(f2bf(v.x), f2bf(v.y), f2bf(v.z), f2bf(v.w));
    *(ushort4*)&xb[(size_t)row * IND + col] = o;
    const float* wp = &Wg[(size_t)col * NE];
    float xv[4] = {v.x, v.y, v.z, v.w};
#pragma unroll
    for (int i = 0; i < 4; ++i) {
      float4 w0 = *(const float4*)&wp[i * NE];
      float4 w1 = *(const float4*)&wp[i * NE + 4];
      acc[0] = fmaf(xv[i], w0.x, acc[0]);
      acc[1] = fmaf(xv[i], w0.y, acc[1]);
      acc[2] = fmaf(xv[i], w0.z, acc[2]);
      acc[3] = fmaf(xv[i], w0.w, acc[3]);
      acc[4] = fmaf(xv[i], w1.x, acc[4]);
      acc[5] = fmaf(xv[i], w1.y, acc[5]);
      acc[6] = fmaf(xv[i], w1.z, acc[6]);
      acc[7] = fmaf(xv[i], w1.w, acc[7]);
    }
  }
#pragma unroll
  for (int off = 32; off; off >>= 1)
#pragma unroll
    for (int e = 0; e < NE; ++e) acc[e] += __shfl_xor(acc[e], off);

#pragma unroll
  for (int e = 0; e < NE; ++e) acc[e] += bg[e];
  float mx = acc[0];
#pragma unroll
  for (int e = 1; e < NE; ++e) mx = fmaxf(mx, acc[e]);
  float s = 0.f;
#pragma unroll
  for (int e = 0; e < NE; ++e) { acc[e] = expf(acc[e] - mx); s += acc[e]; }
  float inv = 1.f / s;
  if (lane < NE) gates[(size_t)row * NE + lane] = acc[lane] * inv;
}

// ---------------------------------------------------------------------------
// Transpose fp32 W -> bf16, both weights in one dispatch.
//   blocks [0,2048):   W1[e][k][n] -> W1t[e][n*1024 + k]      (k linear)
//   blocks [2048,4096): W2[e][k][n] -> W2t[e>>2][n*4096 + (e&3)*1024 + k']
//     with k' = 64*(k/64) + (k%16)*4 + ((k%64)/16)  (matches gemm1's
//     coalesced Hg store; dot product invariant)
// ---------------------------------------------------------------------------
__global__ __launch_bounds__(256) void transpose_w12(
    const float* __restrict__ W1, const float* __restrict__ W2,
    u16* __restrict__ W1t, u16* __restrict__ W2t) {
  __shared__ u16 tile[64][65];
  int bid = blockIdx.x;
  int half = bid >> 11;
  int b2 = bid & 2047;
  int e = b2 >> 8;
  int tb = b2 & 255;
  int r0 = (tb >> 4) * 64;     // input row block (k)
  int c0 = (tb & 15) * 64;     // input col block (n)
  const float* We; u16* Wte; int ostride;
  if (half == 0) {
    We = W1 + (size_t)e * IND * OUTD;
    Wte = W1t + ((size_t)e << 20);
    ostride = 1024;
  } else {
    We = W2 + (size_t)e * IND * OUTD;
    Wte = W2t + ((size_t)(e >> 2) << 22) + (size_t)(e & 3) * 1024;
    ostride = KH2;
  }
  int t = threadIdx.x;
  int tr = t >> 4;
  int s  = t & 15;
  int tc = s * 4;
#pragma unroll
  for (int j = 0; j < 4; ++j) {
    int row = j * 16 + tr;
    float4 v = *(const float4*)&We[(size_t)(r0 + row) * OUTD + c0 + tc];
    tile[row][tc + 0] = f2bf(v.x);
    tile[row][tc + 1] = f2bf(v.y);
    tile[row][tc + 2] = f2bf(v.z);
    tile[row][tc + 3] = f2bf(v.w);
  }
  __syncthreads();
#pragma unroll
  for (int j = 0; j < 4; ++j) {
    int row = j * 16 + tr;     // output row (= input col n)
    ushort4 o;
    if (half == 0) {
      o = make_ushort4(tile[tc + 0][row], tile[tc + 1][row],
                       tile[tc + 2][row], tile[tc + 3][row]);
    } else {
      // k' = 4s + b  <-  k = 16b + s
      o = make_ushort4(tile[s][row], tile[s + 16][row],
                       tile[s + 32][row], tile[s + 48][row]);
    }
    *(ushort4*)&Wte[(size_t)(c0 + row) * ostride + r0 + tc] = o;
  }
}

// ---------------------------------------------------------------------------
// 256x256 GEMM core, BK=64, 8 waves (2x4), 128 KiB LDS, 4 phases/K-tile
// with PHASE-AHEAD fragment reads (WAR-free rotation a0/a1/b0/b1):
//   ph1: LG0; MFMA00(a0,b0); read b1(T);  stage G1(T+1); VM6[G2(T)];  BAR
//   ph2: LG0; MFMA01(a0,b1); read a1(T);  stage G2(T+1);              BAR
//   ph3: LG0; MFMA10(a1,b0);                              VM2[G1(T+1)]; BAR
//   ph4:      MFMA11(a1,b1); read a0,b0(T+1) from next buf;           BAR
// Each MFMA consumes frags read a FULL PHASE earlier -> LG0 ~free.
// Ledger (in-order, 2 loads/slot, G1={s0 A-lo,s1 B-lo,s2 B-hi}=6, G2={s3}=2):
//   VM6 end-ph1(T): queue=[G2(T),G1(T+1)]=8 -> completes G2(T)  (ph2 reads)
//   VM2 end-ph3(T): queue=[G1(T+1),G2(T+1)]=8 -> completes G1(T+1) (ph4 reads)
// Cross-wave safety: each wave's counted VM + following BAR. vmcnt never
// drains mid-loop; LAST tile: VM0 at ph1 (only G2(L) outstanding).
// XOR-swizzle both-sides: linear gload dest, pre-swizzled src, XOR read.
// ---------------------------------------------------------------------------
#define BAR() asm volatile("s_barrier" ::: "memory")
#define VM0() asm volatile("s_waitcnt vmcnt(0)" ::: "memory")
#define VM2() asm volatile("s_waitcnt vmcnt(2)" ::: "memory")
#define VM6() asm volatile("s_waitcnt vmcnt(6)" ::: "memory")
#define LG0()                                            \
  do {                                                   \
    asm volatile("s_waitcnt lgkmcnt(0)" ::: "memory");   \
    __builtin_amdgcn_sched_barrier(0);                   \
  } while (0)

template <int SLOT, int K>
__device__ __forceinline__ void stage_slot(
    const u16* __restrict__ g, char* buf, int k0,
    int ch0, int rsub, int koff, int lbyte) {
#pragma unroll
  for (int j = 0; j < 2; ++j) {
    int ch = ch0 + j;
    int r;
    if constexpr (SLOT == 0)      r = (ch >> 3) * 128 + (ch & 7) * 8 + rsub;
    else if constexpr (SLOT == 3) r = 64 + (ch >> 3) * 128 + (ch & 7) * 8 + rsub;
    else if constexpr (SLOT == 1) r = (ch >> 2) * 64 + (ch & 3) * 8 + rsub;
    else                          r = (ch >> 2) * 64 + 32 + (ch & 3) * 8 + rsub;
    gload_lds16(g + (size_t)r * K + k0 + koff, buf + r * 128 + lbyte);
  }
}

template <int QH>
__device__ __forceinline__ void load_a(const char* rb, int wr, int lr, int hi,
                                       int swr, bf16x8 (&a)[4][2]) {
#pragma unroll
  for (int i = 0; i < 4; ++i)
#pragma unroll
    for (int ks = 0; ks < 2; ++ks)
      a[i][ks] = *(const bf16x8*)(rb + (wr * 128 + QH * 64 + i * 16 + lr) * 128
                                  + ((ks * 64 + hi * 16) ^ swr));
}

template <int NH>
__device__ __forceinline__ void load_b(const char* rb, int wc, int lr, int hi,
                                       int swr, bf16x8 (&b)[2][2]) {
#pragma unroll
  for (int q = 0; q < 2; ++q)
#pragma unroll
    for (int ks = 0; ks < 2; ++ks)
      b[q][ks] = *(const bf16x8*)(rb +
                                  (wc * 64 + (NH * 2 + q) * 16 + lr) * 128
                                  + ((ks * 64 + hi * 16) ^ swr));
}

template <int MH, int NH>
__device__ __forceinline__ void mfma_quad(const bf16x8 (&a)[4][2],
                                          const bf16x8 (&b)[2][2],
                                          f32x4 (&acc)[8][4]) {
  __builtin_amdgcn_s_setprio(1);
#pragma unroll
  for (int i = 0; i < 4; ++i)
#pragma unroll
    for (int q = 0; q < 2; ++q) {
      acc[MH*4+i][NH*2+q] = __builtin_amdgcn_mfma_f32_16x16x32_bf16(
          a[i][0], b[q][0], acc[MH*4+i][NH*2+q], 0, 0, 0);
      acc[MH*4+i][NH*2+q] = __builtin_amdgcn_mfma_f32_16x16x32_bf16(
          a[i][1], b[q][1], acc[MH*4+i][NH*2+q], 0, 0, 0);
    }
  __builtin_amdgcn_s_setprio(0);
}

template <bool LAST, int K>
__device__ __forceinline__ void tile4(
    const u16* __restrict__ pA, const u16* __restrict__ pB,
    const char* rA, const char* rB, char* sA, char* sB, int kN,
    int ch0, int rsub, int koff, int lbyte,
    int wr, int wc, int lr, int hi, int swr,
    bf16x8 (&a0)[4][2], bf16x8 (&a1)[4][2],
    bf16x8 (&b0)[2][2], bf16x8 (&b1)[2][2],
    f32x4 (&acc)[8][4]) {
  // ph1: MFMA00 (a0,b0 read in prev ph4); read b1(T); stage G1(T+1)
  LG0();
  mfma_quad<0, 0>(a0, b0, acc);
  load_b<1>(rB, wc, lr, hi, swr, b1);
  if constexpr (!LAST) {
    stage_slot<0, K>(pA, sA, kN, ch0, rsub, koff, lbyte);
    stage_slot<1, K>(pB, sB, kN, ch0, rsub, koff, lbyte);
    stage_slot<2, K>(pB, sB, kN, ch0, rsub, koff, lbyte);
    VM6();                      // G2(T) complete
  } else {
    VM0();                      // only G2(L) outstanding
  }
  BAR();
  // ph2: MFMA01; read a1(T); stage G2(T+1)
  LG0();
  mfma_quad<0, 1>(a0, b1, acc);
  load_a<1>(rA, wr, lr, hi, swr, a1);
  if constexpr (!LAST)
    stage_slot<3, K>(pA, sA, kN, ch0, rsub, koff, lbyte);
  BAR();
  // ph3: MFMA10
  LG0();
  mfma_quad<1, 0>(a1, b0, acc);
  if constexpr (!LAST) { VM2(); }  // G1(T+1) complete
  BAR();
  // ph4: MFMA11; prefetch a0,b0(T+1) from next buffers
  mfma_quad<1, 1>(a1, b1, acc);
  if constexpr (!LAST) {
    load_a<0>(sA, wr, lr, hi, swr, a0);
    load_b<0>(sB, wc, lr, hi, swr, b0);
  }
  BAR();
}

template <int K>
__device__ __forceinline__ void core256(const u16* __restrict__ pA,
                                        const u16* __restrict__ pB,
                                        char* lds, int t, f32x4 (&acc)[8][4]) {
  constexpr int KT = K / 64;
  static_assert(KT >= 2, "KT must be >= 2");
  const int l = t & 63;
  const int w = t >> 6;
  const int wr = w >> 2, wc = w & 3;
  const int lr = l & 15, hi = l >> 4;
  const int rsub = l >> 3;
  const int koff = ((l & 7) ^ rsub) << 3;  // pre-swizzled source col (elems)
  const int lbyte = (l & 7) * 16;
  const int ch0 = w * 2;
  const int swr = (lr & 7) << 4;           // read-side swizzle (bytes)

  char* A0 = lds;
  char* A1 = lds + 32768;
  char* B0 = lds + 65536;
  char* B1 = lds + 98304;

  bf16x8 a0[4][2], a1[4][2], b0[2][2], b1[2][2];

  // prologue: stage G1(0),G2(0) -> bufs0; VM2 completes G1(0); read a0,b0(0)
  stage_slot<0, K>(pA, A0, 0, ch0, rsub, koff, lbyte);
  stage_slot<1, K>(pB, B0, 0, ch0, rsub, koff, lbyte);
  stage_slot<2, K>(pB, B0, 0, ch0, rsub, koff, lbyte);
  stage_slot<3, K>(pA, A0, 0, ch0, rsub, koff, lbyte);
  VM2(); BAR();
  load_a<0>(A0, wr, lr, hi, swr, a0);
  load_b<0>(B0, wc, lr, hi, swr, b0);

  char *rA = A0, *rB = B0, *sA = A1, *sB = B1;
  for (int T = 0; T < KT - 1; ++T) {
    tile4<false, K>(pA, pB, rA, rB, sA, sB, (T + 1) * 64,
                    ch0, rsub, koff, lbyte, wr, wc, lr, hi, swr,
                    a0, a1, b0, b1, acc);
    char* x = rA; rA = sA; sA = x;
    x = rB; rB = sB; sB = x;
  }
  tile4<true, K>(pA, pB, rA, rB, sA, sB, 0,
                 ch0, rsub, koff, lbyte, wr, wc, lr, hi, swr,
                 a0, a1, b0, b1, acc);
}

// ---------------------------------------------------------------------------
// GEMM1 (one expert-half, 4 experts, full batch):
//   Hg[m][ee*1024 + kperm(n)] = gates[m][eg0+ee]*relu(x@W1_[eg0+ee] + b1)
// kperm: n = 64q+16b+s stored at 64q+4s+b -> one ushort4 store per (m,r).
// grid = 64mb * 4nb * 4ee = 1024
// ---------------------------------------------------------------------------
__global__ __launch_bounds__(512, 2) void gemm1(
    const u16* __restrict__ xb, const u16* __restrict__ W1t,
    const float* __restrict__ b1, const float* __restrict__ gates,
    u16* __restrict__ Hg, int eg0) {
  __shared__ char lds[131072];
  int t = threadIdx.x;
  int nwg = gridDim.x, cpx = nwg >> 3, bid = blockIdx.x;
  int swz = (bid & 7) * cpx + (bid >> 3);  // bijective XCD swizzle (nwg%8==0)
  int nb = swz & 3, ee = (swz >> 2) & 3, mb = swz >> 4;
  int e = eg0 + ee;

  f32x4 acc[8][4] = {};
  core256<1024>(xb + (size_t)mb * 256 * 1024,
                W1t + ((size_t)e << 20) + (size_t)nb * 256 * 1024,
                lds, t, acc);

  int l = t & 63, w = t >> 6, wr = w >> 2, wc = w & 3, lr = l & 15, hi = l >> 4;
  int m0 = mb * 256 + wr * 128 + hi * 4;
  int n0 = nb * 256 + wc * 64 + lr;        // logical col (bias indexing)
  int nst = nb * 256 + wc * 64 + lr * 4;   // permuted store col
  const float* b1e = b1 + e * OUTD;
  float bv[4];
#pragma unroll
  for (int nn = 0; nn < 4; ++nn) bv[nn] = b1e[n0 + nn * 16];
#pragma unroll
  for (int m = 0; m < 8; ++m) {
#pragma unroll
    for (int r = 0; r < 4; ++r) {
      int row = m0 + m * 16 + r;
      float g = gates[(size_t)row * NE + e];
      ushort4 o;
      o.x = f2bf(g * fmaxf(acc[m][0][r] + bv[0], 0.f));
      o.y = f2bf(g * fmaxf(acc[m][1][r] + bv[1], 0.f));
      o.z = f2bf(g * fmaxf(acc[m][2][r] + bv[2], 0.f));
      o.w = f2bf(g * fmaxf(acc[m][3][r] + bv[3], 0.f));
      *(ushort4*)&Hg[(size_t)row * KH2 + ee * 1024 + nst] = o;
    }
  }
}

// ---------------------------------------------------------------------------
// GEMM2 (one expert-half, K=4096, k-permuted A and B consistently):
//   FIRST: out = Hg@W2th + sum_{ee<4} g*b2 ;  else out += same
// grid = 64mb * 4nb = 256  (full chip)
// ---------------------------------------------------------------------------
template <bool FIRST>
__global__ __launch_bounds__(512, 2) void gemm2(
    const u16* __restrict__ Hg, const u16* __restrict__ W2th,
    const float* __restrict__ b2h, const float* __restrict__ gates,
    float* __restrict__ out, int eg0) {
  __shared__ char lds[131072];
  int t = threadIdx.x;
  int nwg = gridDim.x, cpx = nwg >> 3, bid = blockIdx.x;
  int swz = (bid & 7) * cpx + (bid >> 3);
  int nb = swz & 3, mb = swz >> 2;

  f32x4 acc[8][4] = {};
  core256<KH2>(Hg + (size_t)mb * 256 * KH2, W2th + (size_t)nb * 256 * KH2,
               lds, t, acc);

  int l = t & 63, w = t >> 6, wr = w >> 2, wc = w & 3, lr = l & 15, hi = l >> 4;
  int m0 = mb * 256 + wr * 128 + hi * 4;
  int n0 = nb * 256 + wc * 64 + lr;

  float bcol[4][4];
#pragma unroll
  for (int nn = 0; nn < 4; ++nn)
#pragma unroll
    for (int j = 0; j < 4; ++j)
      bcol[nn][j] = b2h[j * OUTD + n0 + nn * 16];

#pragma unroll
  for (int m = 0; m < 8; ++m) {
#pragma unroll
    for (int r = 0; r < 4; ++r) {
      int row = m0 + m * 16 + r;
      float4 ga = *(const float4*)&gates[(size_t)row * NE + eg0];
#pragma unroll
      for (int nn = 0; nn < 4; ++nn) {
        float bias = ga.x * bcol[nn][0] + ga.y * bcol[nn][1] +
                     ga.z * bcol[nn][2] + ga.w * bcol[nn][3];
        size_t oi = (size_t)row * OUTD + n0 + nn * 16;
        float v = acc[m][nn][r] + bias;
        if (FIRST) out[oi] = v;
        else       out[oi] += v;
      }
    }
  }
}

// ---------------------------------------------------------------------------
extern "C" void kernel_launch(void* const* d_in, const int* in_sizes, int n_in,
                              void* d_out, int out_size, void* d_ws, size_t ws_size,
                              hipStream_t stream) {
  (void)in_sizes; (void)n_in; (void)out_size; (void)ws_size;
  const float* text = (const float*)d_in[0];
  const float* tech = (const float*)d_in[1];
  const float* W1   = (const float*)d_in[2];
  const float* b1   = (const float*)d_in[3];
  const float* W2   = (const float*)d_in[4];
  const float* b2   = (const float*)d_in[5];
  const float* Wg   = (const float*)d_in[6];
  const float* bg   = (const float*)d_in[7];
  float* out = (float*)d_out;

  // workspace: 33.5 + 16.8 + 16.8 + 0.5 + 134.2 = 201.85 MB (proven fits)
  char* p = (char*)d_ws;
  u16* xb  = (u16*)p;  p += (size_t)NB * IND * 2;
  u16* W1t = (u16*)p;  p += (size_t)NE * IND * OUTD * 2;
  u16* W2t = (u16*)p;  p += (size_t)NE * OUTD * OUTD * 2;  // 2 halves x [1024][4096]
  float* gates = (float*)p; p += (size_t)NB * NE * 4;
  u16* Hg  = (u16*)p;                                      // [NB][KH2] bf16

  convert_gates<<<dim3(NB / 4), dim3(256), 0, stream>>>(text, tech, Wg, bg, xb, gates);
  transpose_w12<<<dim3(4096), dim3(256), 0, stream>>>(W1, W2, W1t, W2t);

  for (int h = 0; h < 2; ++h) {
    int eg0 = h * 4;
    gemm1<<<dim3(1024), dim3(512), 0, stream>>>(xb, W1t, b1, gates, Hg, eg0);
    const u16* W2th = W2t + ((size_t)h << 22);
    const float* b2h = b2 + (size_t)eg0 * OUTD;
    if (h == 0)
      gemm2<true><<<dim3(256), dim3(512), 0, stream>>>(Hg, W2th, b2h, gates, out, eg0);
    else
      gemm2<false><<<dim3(256), dim3(512), 0, stream>>>(Hg, W2th, b2h, gates, out, eg0);
  }
}

// Round 15
// 570.017 us; speedup vs baseline: 1.7158x; 1.0032x over previous
//
#include <hip/hip_runtime.h>
#include <hip/hip_bf16.h>

// Problem constants
#define NB 16384        // batch rows
#define TEXT_D 768
#define TECH_D 256
#define IND 1024        // IN_D
#define OUTD 1024       // OUT_D
#define NE 8            // experts
#define KH2 4096        // half-hidden K = 4 experts * 1024

typedef unsigned short u16;
typedef __bf16 bf16x8 __attribute__((ext_vector_type(8)));
typedef float f32x4 __attribute__((ext_vector_type(4)));

__device__ __forceinline__ u16 f2bf(float f) {
  union { float f; unsigned int u; } x; x.f = f;
  unsigned int u = x.u;
  return (u16)((u + 0x7FFFu + ((u >> 16) & 1u)) >> 16);
}

__device__ __forceinline__ void gload_lds16(const void* g, void* l) {
  __builtin_amdgcn_global_load_lds(
      (const __attribute__((address_space(1))) unsigned int*)g,
      (__attribute__((address_space(3))) unsigned int*)l, 16, 0, 0);
}

// ---------------------------------------------------------------------------
// Fused: concat->bf16 xb  AND  gates = softmax(x@Wg + bg).
// ---------------------------------------------------------------------------
__global__ __launch_bounds__(256) void convert_gates(
    const float* __restrict__ text, const float* __restrict__ tech,
    const float* __restrict__ Wg, const float* __restrict__ bg,
    u16* __restrict__ xb, float* __restrict__ gates) {
  int t = threadIdx.x;
  int wave = t >> 6, lane = t & 63;
  int row = blockIdx.x * 4 + wave;

  float acc[NE];
#pragma unroll
  for (int e = 0; e < NE; ++e) acc[e] = 0.f;

#pragma unroll
  for (int j = 0; j < 4; ++j) {
    int col = j * 256 + lane * 4;
    float4 v = (j < 3) ? *(const float4*)&text[(size_t)row * TEXT_D + col]
                       : *(const float4*)&tech[(size_t)row * TECH_D + lane * 4];
    ushort4 o = make_ushort4(f2bf(v.x), f2bf(v.y), f2bf(v.z), f2bf(v.w));
    *(ushort4*)&xb[(size_t)row * IND + col] = o;
    const float* wp = &Wg[(size_t)col * NE];
    float xv[4] = {v.x, v.y, v.z, v.w};
#pragma unroll
    for (int i = 0; i < 4; ++i) {
      float4 w0 = *(const float4*)&wp[i * NE];
      float4 w1 = *(const float4*)&wp[i * NE + 4];
      acc[0] = fmaf(xv[i], w0.x, acc[0]);
      acc[1] = fmaf(xv[i], w0.y, acc[1]);
      acc[2] = fmaf(xv[i], w0.z, acc[2]);
      acc[3] = fmaf(xv[i], w0.w, acc[3]);
      acc[4] = fmaf(xv[i], w1.x, acc[4]);
      acc[5] = fmaf(xv[i], w1.y, acc[5]);
      acc[6] = fmaf(xv[i], w1.z, acc[6]);
      acc[7] = fmaf(xv[i], w1.w, acc[7]);
    }
  }
#pragma unroll
  for (int off = 32; off; off >>= 1)
#pragma unroll
    for (int e = 0; e < NE; ++e) acc[e] += __shfl_xor(acc[e], off);

#pragma unroll
  for (int e = 0; e < NE; ++e) acc[e] += bg[e];
  float mx = acc[0];
#pragma unroll
  for (int e = 1; e < NE; ++e) mx = fmaxf(mx, acc[e]);
  float s = 0.f;
#pragma unroll
  for (int e = 0; e < NE; ++e) { acc[e] = expf(acc[e] - mx); s += acc[e]; }
  float inv = 1.f / s;
  if (lane < NE) gates[(size_t)row * NE + lane] = acc[lane] * inv;
}

// ---------------------------------------------------------------------------
// Transpose fp32 W -> bf16, both weights in one dispatch.
//   blocks [0,2048):   W1[e][k][n] -> W1t[e][n*1024 + k]      (k linear)
//   blocks [2048,4096): W2[e][k][n] -> W2t[e>>2][n*4096 + (e&3)*1024 + k']
//     with k' = 64*(k/64) + (k%16)*4 + ((k%64)/16)  (matches gemm1's
//     coalesced Hg store; dot product invariant)
// ---------------------------------------------------------------------------
__global__ __launch_bounds__(256) void transpose_w12(
    const float* __restrict__ W1, const float* __restrict__ W2,
    u16* __restrict__ W1t, u16* __restrict__ W2t) {
  __shared__ u16 tile[64][65];
  int bid = blockIdx.x;
  int half = bid >> 11;
  int b2 = bid & 2047;
  int e = b2 >> 8;
  int tb = b2 & 255;
  int r0 = (tb >> 4) * 64;     // input row block (k)
  int c0 = (tb & 15) * 64;     // input col block (n)
  const float* We; u16* Wte; int ostride;
  if (half == 0) {
    We = W1 + (size_t)e * IND * OUTD;
    Wte = W1t + ((size_t)e << 20);
    ostride = 1024;
  } else {
    We = W2 + (size_t)e * IND * OUTD;
    Wte = W2t + ((size_t)(e >> 2) << 22) + (size_t)(e & 3) * 1024;
    ostride = KH2;
  }
  int t = threadIdx.x;
  int tr = t >> 4;
  int s  = t & 15;
  int tc = s * 4;
#pragma unroll
  for (int j = 0; j < 4; ++j) {
    int row = j * 16 + tr;
    float4 v = *(const float4*)&We[(size_t)(r0 + row) * OUTD + c0 + tc];
    tile[row][tc + 0] = f2bf(v.x);
    tile[row][tc + 1] = f2bf(v.y);
    tile[row][tc + 2] = f2bf(v.z);
    tile[row][tc + 3] = f2bf(v.w);
  }
  __syncthreads();
#pragma unroll
  for (int j = 0; j < 4; ++j) {
    int row = j * 16 + tr;     // output row (= input col n)
    ushort4 o;
    if (half == 0) {
      o = make_ushort4(tile[tc + 0][row], tile[tc + 1][row],
                       tile[tc + 2][row], tile[tc + 3][row]);
    } else {
      // k' = 4s + b  <-  k = 16b + s
      o = make_ushort4(tile[s][row], tile[s + 16][row],
                       tile[s + 32][row], tile[s + 48][row]);
    }
    *(ushort4*)&Wte[(size_t)(c0 + row) * ostride + r0 + tc] = o;
  }
}

// ---------------------------------------------------------------------------
// 256x256 GEMM core, BK=64, 8 waves (2x4), 128 KiB LDS, 4 phases/K-tile
// with PHASE-AHEAD fragment reads (WAR-free rotation a0/a1/b0/b1)  [r12]
// + T19 sched_group_barrier pinning an MFMA<->DS_READ<->VMEM interleave
// inside each phase. Diagnosis (r13/r14 counters): per SIMD each phase was
// [both waves' 16-MFMA cluster: 620cyc, DS idle] then [both waves' ds_reads:
// 750cyc, MFMA idle] -> serial 1370 ~= observed 1290. The phase-ahead frag
// reads make each phase's MFMA independent of its own ds_reads, so an
// issue-level interleave is legal; SGB pins it so both pipes run together.
// Sync structure (waits/barriers/buffers) is byte-identical to r12/r14.
// Ledger (in-order, 2 loads/slot, G1={s0 A-lo,s1 B-lo,s2 B-hi}=6, G2={s3}=2):
//   VM6 end-ph1(T): queue=[G2(T),G1(T+1)]=8 -> completes G2(T)  (ph2 reads)
//   VM2 end-ph3(T): queue=[G1(T+1),G2(T+1)]=8 -> completes G1(T+1) (ph4 reads)
// XOR-swizzle both-sides: linear gload dest, pre-swizzled src, XOR read.
// ---------------------------------------------------------------------------
#define BAR() asm volatile("s_barrier" ::: "memory")
#define VM0() asm volatile("s_waitcnt vmcnt(0)" ::: "memory")
#define VM2() asm volatile("s_waitcnt vmcnt(2)" ::: "memory")
#define VM6() asm volatile("s_waitcnt vmcnt(6)" ::: "memory")
#define LG0()                                            \
  do {                                                   \
    asm volatile("s_waitcnt lgkmcnt(0)" ::: "memory");   \
    __builtin_amdgcn_sched_barrier(0);                   \
  } while (0)
// sched_group_barrier masks (LLVM): MFMA=0x8, VMEM_READ=0x20, DS_READ=0x100
#define SGB(m, n) __builtin_amdgcn_sched_group_barrier(m, n, 0)

template <int SLOT, int K>
__device__ __forceinline__ void stage_slot(
    const u16* __restrict__ g, char* buf, int k0,
    int ch0, int rsub, int koff, int lbyte) {
#pragma unroll
  for (int j = 0; j < 2; ++j) {
    int ch = ch0 + j;
    int r;
    if constexpr (SLOT == 0)      r = (ch >> 3) * 128 + (ch & 7) * 8 + rsub;
    else if constexpr (SLOT == 3) r = 64 + (ch >> 3) * 128 + (ch & 7) * 8 + rsub;
    else if constexpr (SLOT == 1) r = (ch >> 2) * 64 + (ch & 3) * 8 + rsub;
    else                          r = (ch >> 2) * 64 + 32 + (ch & 3) * 8 + rsub;
    gload_lds16(g + (size_t)r * K + k0 + koff, buf + r * 128 + lbyte);
  }
}

template <int QH>
__device__ __forceinline__ void load_a(const char* rb, int wr, int lr, int hi,
                                       int swr, bf16x8 (&a)[4][2]) {
#pragma unroll
  for (int i = 0; i < 4; ++i)
#pragma unroll
    for (int ks = 0; ks < 2; ++ks)
      a[i][ks] = *(const bf16x8*)(rb + (wr * 128 + QH * 64 + i * 16 + lr) * 128
                                  + ((ks * 64 + hi * 16) ^ swr));
}

template <int NH>
__device__ __forceinline__ void load_b(const char* rb, int wc, int lr, int hi,
                                       int swr, bf16x8 (&b)[2][2]) {
#pragma unroll
  for (int q = 0; q < 2; ++q)
#pragma unroll
    for (int ks = 0; ks < 2; ++ks)
      b[q][ks] = *(const bf16x8*)(rb +
                                  (wc * 64 + (NH * 2 + q) * 16 + lr) * 128
                                  + ((ks * 64 + hi * 16) ^ swr));
}

template <int MH, int NH>
__device__ __forceinline__ void mfma_quad(const bf16x8 (&a)[4][2],
                                          const bf16x8 (&b)[2][2],
                                          f32x4 (&acc)[8][4]) {
  __builtin_amdgcn_s_setprio(1);
#pragma unroll
  for (int i = 0; i < 4; ++i)
#pragma unroll
    for (int q = 0; q < 2; ++q) {
      acc[MH*4+i][NH*2+q] = __builtin_amdgcn_mfma_f32_16x16x32_bf16(
          a[i][0], b[q][0], acc[MH*4+i][NH*2+q], 0, 0, 0);
      acc[MH*4+i][NH*2+q] = __builtin_amdgcn_mfma_f32_16x16x32_bf16(
          a[i][1], b[q][1], acc[MH*4+i][NH*2+q], 0, 0, 0);
    }
  __builtin_amdgcn_s_setprio(0);
}

template <bool LAST, int K>
__device__ __forceinline__ void tile4(
    const u16* __restrict__ pA, const u16* __restrict__ pB,
    const char* rA, const char* rB, char* sA, char* sB, int kN,
    int ch0, int rsub, int koff, int lbyte,
    int wr, int wc, int lr, int hi, int swr,
    bf16x8 (&a0)[4][2], bf16x8 (&a1)[4][2],
    bf16x8 (&b0)[2][2], bf16x8 (&b1)[2][2],
    f32x4 (&acc)[8][4]) {
  // ph1: MFMA00 (a0,b0 read in prev ph4); read b1(T); stage G1(T+1)
  LG0();
  mfma_quad<0, 0>(a0, b0, acc);
  load_b<1>(rB, wc, lr, hi, swr, b1);
  if constexpr (!LAST) {
    stage_slot<0, K>(pA, sA, kN, ch0, rsub, koff, lbyte);
    stage_slot<1, K>(pB, sB, kN, ch0, rsub, koff, lbyte);
    stage_slot<2, K>(pB, sB, kN, ch0, rsub, koff, lbyte);
    // pin: {4 MFMA, 1 ds_read, 2 vmem} x3 + {4 MFMA, 1 ds_read}
    SGB(0x8, 4); SGB(0x100, 1); SGB(0x20, 2);
    SGB(0x8, 4); SGB(0x100, 1); SGB(0x20, 2);
    SGB(0x8, 4); SGB(0x100, 1); SGB(0x20, 2);
    SGB(0x8, 4); SGB(0x100, 1);
    VM6();                      // G2(T) complete
  } else {
    VM0();                      // only G2(L) outstanding
  }
  BAR();
  // ph2: MFMA01; read a1(T); stage G2(T+1)
  LG0();
  mfma_quad<0, 1>(a0, b1, acc);
  load_a<1>(rA, wr, lr, hi, swr, a1);
  if constexpr (!LAST) {
    stage_slot<3, K>(pA, sA, kN, ch0, rsub, koff, lbyte);
    // pin: vmem first, then {2 MFMA, 1 ds_read} x8
    SGB(0x20, 2);
    SGB(0x8, 2); SGB(0x100, 1);
    SGB(0x8, 2); SGB(0x100, 1);
    SGB(0x8, 2); SGB(0x100, 1);
    SGB(0x8, 2); SGB(0x100, 1);
    SGB(0x8, 2); SGB(0x100, 1);
    SGB(0x8, 2); SGB(0x100, 1);
    SGB(0x8, 2); SGB(0x100, 1);
    SGB(0x8, 2); SGB(0x100, 1);
  }
  BAR();
  // ph3: MFMA10 (pure MFMA)
  LG0();
  mfma_quad<1, 0>(a1, b0, acc);
  if constexpr (!LAST) { VM2(); }  // G1(T+1) complete
  BAR();
  // ph4: MFMA11; prefetch a0,b0(T+1) from next buffers
  mfma_quad<1, 1>(a1, b1, acc);
  if constexpr (!LAST) {
    load_a<0>(sA, wr, lr, hi, swr, a0);
    load_b<0>(sB, wc, lr, hi, swr, b0);
    // pin: {2 MFMA, 2 ds_read} x6 + {4 MFMA}
    SGB(0x8, 2); SGB(0x100, 2);
    SGB(0x8, 2); SGB(0x100, 2);
    SGB(0x8, 2); SGB(0x100, 2);
    SGB(0x8, 2); SGB(0x100, 2);
    SGB(0x8, 2); SGB(0x100, 2);
    SGB(0x8, 2); SGB(0x100, 2);
    SGB(0x8, 4);
  }
  BAR();
}

template <int K>
__device__ __forceinline__ void core256(const u16* __restrict__ pA,
                                        const u16* __restrict__ pB,
                                        char* lds, int t, f32x4 (&acc)[8][4]) {
  constexpr int KT = K / 64;
  static_assert(KT >= 2, "KT must be >= 2");
  const int l = t & 63;
  const int w = t >> 6;
  const int wr = w >> 2, wc = w & 3;
  const int lr = l & 15, hi = l >> 4;
  const int rsub = l >> 3;
  const int koff = ((l & 7) ^ rsub) << 3;  // pre-swizzled source col (elems)
  const int lbyte = (l & 7) * 16;
  const int ch0 = w * 2;
  const int swr = (lr & 7) << 4;           // read-side swizzle (bytes)

  char* A0 = lds;
  char* A1 = lds + 32768;
  char* B0 = lds + 65536;
  char* B1 = lds + 98304;

  bf16x8 a0[4][2], a1[4][2], b0[2][2], b1[2][2];

  // prologue: stage G1(0),G2(0) -> bufs0; VM2 completes G1(0); read a0,b0(0)
  stage_slot<0, K>(pA, A0, 0, ch0, rsub, koff, lbyte);
  stage_slot<1, K>(pB, B0, 0, ch0, rsub, koff, lbyte);
  stage_slot<2, K>(pB, B0, 0, ch0, rsub, koff, lbyte);
  stage_slot<3, K>(pA, A0, 0, ch0, rsub, koff, lbyte);
  VM2(); BAR();
  load_a<0>(A0, wr, lr, hi, swr, a0);
  load_b<0>(B0, wc, lr, hi, swr, b0);

  char *rA = A0, *rB = B0, *sA = A1, *sB = B1;
  for (int T = 0; T < KT - 1; ++T) {
    tile4<false, K>(pA, pB, rA, rB, sA, sB, (T + 1) * 64,
                    ch0, rsub, koff, lbyte, wr, wc, lr, hi, swr,
                    a0, a1, b0, b1, acc);
    char* x = rA; rA = sA; sA = x;
    x = rB; rB = sB; sB = x;
  }
  tile4<true, K>(pA, pB, rA, rB, sA, sB, 0,
                 ch0, rsub, koff, lbyte, wr, wc, lr, hi, swr,
                 a0, a1, b0, b1, acc);
}

// ---------------------------------------------------------------------------
// GEMM1 (one expert-half, 4 experts, full batch):
//   Hg[m][ee*1024 + kperm(n)] = gates[m][eg0+ee]*relu(x@W1_[eg0+ee] + b1)
// kperm: n = 64q+16b+s stored at 64q+4s+b -> one ushort4 store per (m,r).
// grid = 64mb * 4nb * 4ee = 1024
// ---------------------------------------------------------------------------
__global__ __launch_bounds__(512, 2) void gemm1(
    const u16* __restrict__ xb, const u16* __restrict__ W1t,
    const float* __restrict__ b1, const float* __restrict__ gates,
    u16* __restrict__ Hg, int eg0) {
  __shared__ char lds[131072];
  int t = threadIdx.x;
  int nwg = gridDim.x, cpx = nwg >> 3, bid = blockIdx.x;
  int swz = (bid & 7) * cpx + (bid >> 3);  // bijective XCD swizzle (nwg%8==0)
  int nb = swz & 3, ee = (swz >> 2) & 3, mb = swz >> 4;
  int e = eg0 + ee;

  f32x4 acc[8][4] = {};
  core256<1024>(xb + (size_t)mb * 256 * 1024,
                W1t + ((size_t)e << 20) + (size_t)nb * 256 * 1024,
                lds, t, acc);

  int l = t & 63, w = t >> 6, wr = w >> 2, wc = w & 3, lr = l & 15, hi = l >> 4;
  int m0 = mb * 256 + wr * 128 + hi * 4;
  int n0 = nb * 256 + wc * 64 + lr;        // logical col (bias indexing)
  int nst = nb * 256 + wc * 64 + lr * 4;   // permuted store col
  const float* b1e = b1 + e * OUTD;
  float bv[4];
#pragma unroll
  for (int nn = 0; nn < 4; ++nn) bv[nn] = b1e[n0 + nn * 16];
#pragma unroll
  for (int m = 0; m < 8; ++m) {
#pragma unroll
    for (int r = 0; r < 4; ++r) {
      int row = m0 + m * 16 + r;
      float g = gates[(size_t)row * NE + e];
      ushort4 o;
      o.x = f2bf(g * fmaxf(acc[m][0][r] + bv[0], 0.f));
      o.y = f2bf(g * fmaxf(acc[m][1][r] + bv[1], 0.f));
      o.z = f2bf(g * fmaxf(acc[m][2][r] + bv[2], 0.f));
      o.w = f2bf(g * fmaxf(acc[m][3][r] + bv[3], 0.f));
      *(ushort4*)&Hg[(size_t)row * KH2 + ee * 1024 + nst] = o;
    }
  }
}

// ---------------------------------------------------------------------------
// GEMM2 (one expert-half, K=4096, k-permuted A and B consistently):
//   FIRST: out = Hg@W2th + sum_{ee<4} g*b2 ;  else out += same
// grid = 64mb * 4nb = 256  (full chip)
// ---------------------------------------------------------------------------
template <bool FIRST>
__global__ __launch_bounds__(512, 2) void gemm2(
    const u16* __restrict__ Hg, const u16* __restrict__ W2th,
    const float* __restrict__ b2h, const float* __restrict__ gates,
    float* __restrict__ out, int eg0) {
  __shared__ char lds[131072];
  int t = threadIdx.x;
  int nwg = gridDim.x, cpx = nwg >> 3, bid = blockIdx.x;
  int swz = (bid & 7) * cpx + (bid >> 3);
  int nb = swz & 3, mb = swz >> 2;

  f32x4 acc[8][4] = {};
  core256<KH2>(Hg + (size_t)mb * 256 * KH2, W2th + (size_t)nb * 256 * KH2,
               lds, t, acc);

  int l = t & 63, w = t >> 6, wr = w >> 2, wc = w & 3, lr = l & 15, hi = l >> 4;
  int m0 = mb * 256 + wr * 128 + hi * 4;
  int n0 = nb * 256 + wc * 64 + lr;

  float bcol[4][4];
#pragma unroll
  for (int nn = 0; nn < 4; ++nn)
#pragma unroll
    for (int j = 0; j < 4; ++j)
      bcol[nn][j] = b2h[j * OUTD + n0 + nn * 16];

#pragma unroll
  for (int m = 0; m < 8; ++m) {
#pragma unroll
    for (int r = 0; r < 4; ++r) {
      int row = m0 + m * 16 + r;
      float4 ga = *(const float4*)&gates[(size_t)row * NE + eg0];
#pragma unroll
      for (int nn = 0; nn < 4; ++nn) {
        float bias = ga.x * bcol[nn][0] + ga.y * bcol[nn][1] +
                     ga.z * bcol[nn][2] + ga.w * bcol[nn][3];
        size_t oi = (size_t)row * OUTD + n0 + nn * 16;
        float v = acc[m][nn][r] + bias;
        if (FIRST) out[oi] = v;
        else       out[oi] += v;
      }
    }
  }
}

// ---------------------------------------------------------------------------
extern "C" void kernel_launch(void* const* d_in, const int* in_sizes, int n_in,
                              void* d_out, int out_size, void* d_ws, size_t ws_size,
                              hipStream_t stream) {
  (void)in_sizes; (void)n_in; (void)out_size; (void)ws_size;
  const float* text = (const float*)d_in[0];
  const float* tech = (const float*)d_in[1];
  const float* W1   = (const float*)d_in[2];
  const float* b1   = (const float*)d_in[3];
  const float* W2   = (const float*)d_in[4];
  const float* b2   = (const float*)d_in[5];
  const float* Wg   = (const float*)d_in[6];
  const float* bg   = (const float*)d_in[7];
  float* out = (float*)d_out;

  // workspace: 33.5 + 16.8 + 16.8 + 0.5 + 134.2 = 201.85 MB (proven fits)
  char* p = (char*)d_ws;
  u16* xb  = (u16*)p;  p += (size_t)NB * IND * 2;
  u16* W1t = (u16*)p;  p += (size_t)NE * IND * OUTD * 2;
  u16* W2t = (u16*)p;  p += (size_t)NE * OUTD * OUTD * 2;  // 2 halves x [1024][4096]
  float* gates = (float*)p; p += (size_t)NB * NE * 4;
  u16* Hg  = (u16*)p;                                      // [NB][KH2] bf16

  convert_gates<<<dim3(NB / 4), dim3(256), 0, stream>>>(text, tech, Wg, bg, xb, gates);
  transpose_w12<<<dim3(4096), dim3(256), 0, stream>>>(W1, W2, W1t, W2t);

  for (int h = 0; h < 2; ++h) {
    int eg0 = h * 4;
    gemm1<<<dim3(1024), dim3(512), 0, stream>>>(xb, W1t, b1, gates, Hg, eg0);
    const u16* W2th = W2t + ((size_t)h << 22);
    const float* b2h = b2 + (size_t)eg0 * OUTD;
    if (h == 0)
      gemm2<true><<<dim3(256), dim3(512), 0, stream>>>(Hg, W2th, b2h, gates, out, eg0);
    else
      gemm2<false><<<dim3(256), dim3(512), 0, stream>>>(Hg, W2th, b2h, gates, out, eg0);
  }
}